// Round 15
// baseline (68.567 us; speedup 1.0000x reference)
//
#include <hip/hip_runtime.h>
#include <hip/hip_bf16.h>

// proto_net_loss, 4 dispatches. All MFMA operands fragment-packed (1KB loads):
//  prep:   W1P, W2T, XbP (fragment-packed bf16)
//  gemm1:  FRAG-SPLIT 640 blocks x 4 waves (wave = 16 rows x 32 cols, full K=512)
//          H(packed bf16) = X @ W1 + per-16-row-strip BN partial stats
//  gemm2:  [BN finalize in head, 640 partials] Z(packed) = relu(H*sc+sh)@W2 + norms
//  dist:   D = n1[i]+n2[j]-2*Z1@Z2^T; packed Z loads, float4 stores, XCD swizzle

#define LAT 512
#define HID 128
#define EPSV 1e-5f

typedef __attribute__((ext_vector_type(8))) short bf16x8;
typedef __attribute__((ext_vector_type(4))) float f32x4;

__device__ __forceinline__ unsigned short f2bf(float x) {  // RTNE
  unsigned int u = __builtin_bit_cast(unsigned int, x);
  return (unsigned short)((u + 0x7fffu + ((u >> 16) & 1u)) >> 16);
}
__device__ __forceinline__ float bf2f(unsigned short h) {
  unsigned int u = ((unsigned int)h) << 16;
  return __builtin_bit_cast(float, u);
}
// packed store offset for acc[f][0..3] by lane (l15,lq) into [rows][128] tensor
__device__ __forceinline__ size_t pack4_off(int strip, int f, int l15, int lq) {
  return (size_t)strip * 2048 + (size_t)(f >> 1) * 512 + (size_t)l15 * 32 +
         (size_t)(((f & 1) * 2 + (lq >> 1)) * 8 + (lq & 1) * 4);
}

// ---------------- prep: W1P packed, W2T transposed, XbP packed (r13-verified) ----
__global__ __launch_bounds__(256) void k_prep(const float* __restrict__ W1,
                                              const float* __restrict__ W2,
                                              const float* __restrict__ X1,
                                              const float* __restrict__ X2, int nx,
                                              unsigned short* __restrict__ W1P,
                                              unsigned short* __restrict__ W2T,
                                              unsigned short* __restrict__ XbP) {
  __shared__ float T[64][65];
  const int t = threadIdx.x;
  int bi = blockIdx.x;
  if (bi >= 20) {
    const size_t base = (size_t)(bi - 20) * 2048 + (size_t)t * 8;
    const size_t nxe = (size_t)nx * LAT;
    const float* src = (base < nxe) ? (X1 + base) : (X2 + (base - nxe));
    const float4 a = *(const float4*)src;
    const float4 b = *(const float4*)(src + 4);
    const int row = (int)(base >> 9);
    const int k = (int)(base & 511);
    const int st = row >> 4, l15 = row & 15;
    const int tf = k >> 5, lq = (k >> 3) & 3;
    const size_t off = ((((size_t)st * 16 + tf) * 16 + l15) * 4 + lq) * 8;
    const ushort4 o0 = {f2bf(a.x), f2bf(a.y), f2bf(a.z), f2bf(a.w)};
    const ushort4 o1 = {f2bf(b.x), f2bf(b.y), f2bf(b.z), f2bf(b.w)};
    *(ushort4*)(XbP + off) = o0;
    *(ushort4*)(XbP + off + 4) = o1;
    return;
  }
  if (bi < 16) {  // W1 -> W1P
    const int tk = bi >> 1, tn = bi & 1;
    const int k0 = tk * 64, n0 = tn * 64;
    {
      const int rr = t >> 4, cc = (t & 15) * 4;
#pragma unroll
      for (int i = 0; i < 4; ++i) {
        const int r = rr + i * 16;
        const float4 v = *(const float4*)(W1 + (size_t)(k0 + r) * HID + n0 + cc);
        T[cc + 0][r] = v.x; T[cc + 1][r] = v.y; T[cc + 2][r] = v.z; T[cc + 3][r] = v.w;
      }
    }
    __syncthreads();
    {
      const int nn = t >> 2, q = (t & 3) * 16;
      const int n = n0 + nn;
      const int f = n >> 4, l15 = n & 15;
#pragma unroll
      for (int e8 = 0; e8 < 2; ++e8) {
        const int kq = q + e8 * 8;
        const int kk = k0 + kq;
        const int tf = kk >> 5, lq = (kk >> 3) & 3;
        const size_t off = ((((size_t)f * 16 + tf) * 16 + l15) * 4 + lq) * 8;
        const ushort4 lo = {f2bf(T[nn][kq + 0]), f2bf(T[nn][kq + 1]),
                            f2bf(T[nn][kq + 2]), f2bf(T[nn][kq + 3])};
        const ushort4 hi = {f2bf(T[nn][kq + 4]), f2bf(T[nn][kq + 5]),
                            f2bf(T[nn][kq + 6]), f2bf(T[nn][kq + 7])};
        *(ushort4*)(W1P + off) = lo;
        *(ushort4*)(W1P + off + 4) = hi;
      }
    }
  } else {  // W2 -> W2T
    bi -= 16;
    const int tk = bi >> 1, tn = bi & 1;
    const int k0 = tk * 64, n0 = tn * 64;
    {
      const int rr = t >> 4, cc = (t & 15) * 4;
#pragma unroll
      for (int i = 0; i < 4; ++i) {
        const int r = rr + i * 16;
        const float4 v = *(const float4*)(W2 + (size_t)(k0 + r) * HID + n0 + cc);
        T[cc + 0][r] = v.x; T[cc + 1][r] = v.y; T[cc + 2][r] = v.z; T[cc + 3][r] = v.w;
      }
    }
    __syncthreads();
    {
      const int nn = t >> 2, q = (t & 3) * 16;
      unsigned short* dp = W2T + (size_t)(n0 + nn) * HID + k0 + q;
#pragma unroll
      for (int j = 0; j < 4; ++j) {
        ushort4 o = {f2bf(T[nn][q + j * 4 + 0]), f2bf(T[nn][q + j * 4 + 1]),
                     f2bf(T[nn][q + j * 4 + 2]), f2bf(T[nn][q + j * 4 + 3])};
        *(ushort4*)(dp + j * 4) = o;
      }
    }
  }
}

// ---------------- gemm1: frag-split, 640 blocks x 4 waves, packed operands ----------
// wave w: frags f = 2w, 2w+1 over one 16-row strip (= blockIdx), full K=512.
__global__ __launch_bounds__(256) void k_gemm1(
    const unsigned short* __restrict__ XbP,
    const unsigned short* __restrict__ W1P, unsigned short* __restrict__ H,
    float* __restrict__ pS, float* __restrict__ pQ) {
  __shared__ float sS[4][HID], sQ[4][HID];
  const int tid = threadIdx.x, w = tid >> 6, lane = tid & 63;
  const int l15 = lane & 15, lq = lane >> 4;
  const int b = (int)blockIdx.x;  // strip
  const unsigned short* xp = XbP + (size_t)b * 8192 + (size_t)l15 * 32 + lq * 8;
  const unsigned short* wp = W1P + (size_t)l15 * 32 + lq * 8;
  f32x4 acc[2];
  acc[0] = (f32x4){0.f, 0.f, 0.f, 0.f};
  acc[1] = (f32x4){0.f, 0.f, 0.f, 0.f};
#pragma unroll
  for (int t = 0; t < 16; ++t) {
    const bf16x8 xv = *(const bf16x8*)(xp + (size_t)t * 512);
#pragma unroll
    for (int ff = 0; ff < 2; ++ff) {
      const int f = w * 2 + ff;
      const bf16x8 afr = *(const bf16x8*)(wp + (size_t)(f * 16 + t) * 512);
      acc[ff] = __builtin_amdgcn_mfma_f32_16x16x32_bf16(afr, xv, acc[ff], 0, 0, 0);
    }
  }
  // H store (packed) + per-strip stats
#pragma unroll
  for (int ff = 0; ff < 2; ++ff) {
    const int f = w * 2 + ff;
    ushort4 hz = {f2bf(acc[ff][0]), f2bf(acc[ff][1]), f2bf(acc[ff][2]), f2bf(acc[ff][3])};
    *(ushort4*)(H + pack4_off(b, f, l15, lq)) = hz;
    f32x4 s = acc[ff];
    f32x4 q = acc[ff] * acc[ff];
#pragma unroll
    for (int r = 0; r < 4; ++r) {
      s[r] += __shfl_xor(s[r], 1, 64);
      q[r] += __shfl_xor(q[r], 1, 64);
      s[r] += __shfl_xor(s[r], 2, 64);
      q[r] += __shfl_xor(q[r], 2, 64);
    }
    if ((l15 & 3) == 0) {
      *(f32x4*)&sS[l15 >> 2][f * 16 + lq * 4] = s;
      *(f32x4*)&sQ[l15 >> 2][f * 16 + lq * 4] = q;
    }
  }
  __syncthreads();
  if (tid < HID) {
    const float s = sS[0][tid] + sS[1][tid] + sS[2][tid] + sS[3][tid];
    const float q = sQ[0][tid] + sQ[1][tid] + sQ[2][tid] + sQ[3][tid];
    pS[(size_t)b * HID + tid] = s;
    pQ[(size_t)b * HID + tid] = q;
  }
}

// ---------------- gemm2: finalize-in-head (640 partials) + Z(packed) + norms ------
__global__ __launch_bounds__(256) void k_gemm2(
    const unsigned short* __restrict__ H,
    const unsigned short* __restrict__ W2T,
    const float* __restrict__ pS, const float* __restrict__ pQ,
    const float* __restrict__ gamma, const float* __restrict__ beta,
    unsigned short* __restrict__ Z, float* __restrict__ nrm,
    int pb1, int pnblk, float n1c, float n2c, int nx) {
  __shared__ float s_sc[HID], s_sh[HID];
  __shared__ float t0[2][HID], t1[2][HID];
  const int tid = threadIdx.x, wid = tid >> 6, lane = tid & 63;
  const int l15 = lane & 15, lq = lane >> 4, lk8 = lq * 8;
  const int row0 = (int)blockIdx.x * 64 + wid * 16;
  const bool set1 = ((int)blockIdx.x * 64) < nx;
  {
    const int col = tid & 127, half = tid >> 7;
    const int b0 = set1 ? 0 : pb1;
    const int nb = set1 ? pb1 : (pnblk - pb1);
    float s = 0.f, q = 0.f;
#pragma unroll 4
    for (int b = half; b < nb; b += 2) {
      s += pS[(size_t)(b0 + b) * HID + col];
      q += pQ[(size_t)(b0 + b) * HID + col];
    }
    t0[half][col] = s;
    t1[half][col] = q;
  }
  __syncthreads();
  if (tid < HID) {
    const float s = t0[0][tid] + t0[1][tid];
    const float q = t1[0][tid] + t1[1][tid];
    const float n = set1 ? n1c : n2c;
    const float mean = s / n;
    const float var = q / n - mean * mean;
    const float rstd = rsqrtf(var + EPSV);
    const float scale = gamma[tid] * rstd;
    s_sc[tid] = scale;
    s_sh[tid] = beta[tid] - mean * scale;
  }
  __syncthreads();
  const int strip = row0 >> 4;
  const unsigned short* hptr = H + (size_t)strip * 2048 + (size_t)l15 * 32 + lk8;
  f32x4 acc[8];
#pragma unroll
  for (int f = 0; f < 8; ++f) acc[f] = (f32x4){0.f, 0.f, 0.f, 0.f};
#pragma unroll
  for (int s = 0; s < 4; ++s) {
    const int k = s * 32 + lk8;
    const bf16x8 hv = *(const bf16x8*)(hptr + (size_t)s * 512);
    const float4 c0 = *(const float4*)&s_sc[k];
    const float4 c1 = *(const float4*)&s_sc[k + 4];
    const float4 d0 = *(const float4*)&s_sh[k];
    const float4 d1 = *(const float4*)&s_sh[k + 4];
    const float cc[8] = {c0.x, c0.y, c0.z, c0.w, c1.x, c1.y, c1.z, c1.w};
    const float dd[8] = {d0.x, d0.y, d0.z, d0.w, d1.x, d1.y, d1.z, d1.w};
    bf16x8 bfr;
#pragma unroll
    for (int i = 0; i < 8; ++i) {
      const float a = fmaxf(fmaf(bf2f((unsigned short)hv[i]), cc[i], dd[i]), 0.f);
      bfr[i] = (short)f2bf(a);
    }
#pragma unroll
    for (int f = 0; f < 8; ++f) {
      const bf16x8 afr = *(const bf16x8*)(W2T + (size_t)(f * 16 + l15) * HID + k);
      acc[f] = __builtin_amdgcn_mfma_f32_16x16x32_bf16(afr, bfr, acc[f], 0, 0, 0);
    }
  }
  float rn = 0.f;
#pragma unroll
  for (int f = 0; f < 8; ++f) {
    rn += acc[f][0] * acc[f][0] + acc[f][1] * acc[f][1] +
          acc[f][2] * acc[f][2] + acc[f][3] * acc[f][3];
    ushort4 z4 = {f2bf(acc[f][0]), f2bf(acc[f][1]), f2bf(acc[f][2]), f2bf(acc[f][3])};
    *(ushort4*)(Z + pack4_off(strip, f, l15, lq)) = z4;
  }
  rn += __shfl_xor(rn, 16, 64);
  rn += __shfl_xor(rn, 32, 64);
  if (lane < 16) nrm[row0 + l15] = rn;
}

// ---------------- dist: packed Z loads, float4 stores, XCD swizzle ----------------
__global__ __launch_bounds__(256) void k_dist(const unsigned short* __restrict__ Z1b,
                                              const unsigned short* __restrict__ Z2b,
                                              const float* __restrict__ n1,
                                              const float* __restrict__ n2,
                                              float* __restrict__ D, int NY, int ntx) {
  const int nwg = (int)gridDim.x;
  const int cpx = nwg >> 3;
  const int bid = (int)blockIdx.x;
  const int wgid = (bid & 7) * cpx + (bid >> 3);
  const int tby = wgid / ntx, tbx = wgid - tby * ntx;

  const int tid = threadIdx.x;
  const int wid = tid >> 6, lane = tid & 63;
  const int wr = wid >> 1, wc = wid & 1;
  const int rowB = tby * 128 + wr * 64;
  const int colB = tbx * 128 + wc * 64;
  const int l15 = lane & 15, lq = lane >> 4;
  const unsigned short* Ap = Z1b + (size_t)(rowB >> 4) * 2048 + (size_t)l15 * 32 + lq * 8;
  const unsigned short* Bp = Z2b + (size_t)(colB >> 4) * 2048 + (size_t)l15 * 32 + lq * 8;
  f32x4 acc[4][4];
#pragma unroll
  for (int i = 0; i < 4; ++i)
#pragma unroll
    for (int j = 0; j < 4; ++j) acc[i][j] = (f32x4){0.f, 0.f, 0.f, 0.f};
#pragma unroll
  for (int s = 0; s < 4; ++s) {
    bf16x8 a[4], b[4];
#pragma unroll
    for (int i = 0; i < 4; ++i) a[i] = *(const bf16x8*)(Ap + (size_t)i * 2048 + (size_t)s * 512);
#pragma unroll
    for (int j = 0; j < 4; ++j) b[j] = *(const bf16x8*)(Bp + (size_t)j * 2048 + (size_t)s * 512);
#pragma unroll
    for (int i = 0; i < 4; ++i)
#pragma unroll
      for (int j = 0; j < 4; ++j)
        acc[i][j] = __builtin_amdgcn_mfma_f32_16x16x32_bf16(b[j], a[i], acc[i][j], 0, 0, 0);
  }
  const int cq = lq * 4;
  float na[4];
#pragma unroll
  for (int i = 0; i < 4; ++i) na[i] = n1[rowB + i * 16 + l15];
#pragma unroll
  for (int j = 0; j < 4; ++j) {
    const float4 nbv = *(const float4*)(n2 + colB + j * 16 + cq);
#pragma unroll
    for (int i = 0; i < 4; ++i) {
      float4 o;
      o.x = na[i] + nbv.x - 2.f * acc[i][j][0];
      o.y = na[i] + nbv.y - 2.f * acc[i][j][1];
      o.z = na[i] + nbv.z - 2.f * acc[i][j][2];
      o.w = na[i] + nbv.w - 2.f * acc[i][j][3];
      *(float4*)(D + (size_t)(rowB + i * 16 + l15) * NY + colB + j * 16 + cq) = o;
    }
  }
}

extern "C" void kernel_launch(void* const* d_in, const int* in_sizes, int n_in,
                              void* d_out, int out_size, void* d_ws, size_t ws_size,
                              hipStream_t stream) {
  const float* variations = (const float*)d_in[0];
  const float* exemplar   = (const float*)d_in[1];
  const float* w1         = (const float*)d_in[2];
  const float* gamma      = (const float*)d_in[3];
  const float* beta       = (const float*)d_in[4];
  const float* w2         = (const float*)d_in[5];
  float* D = (float*)d_out;

  const int nx = in_sizes[0] / LAT;  // 8192
  const int ny = in_sizes[1] / LAT;  // 2048
  const int nrows = nx + ny;         // 10240
  const int nst = nrows / 16;        // 640 strips (gemm1 grid + partial count)
  const int pb1 = nx / 16;           // 512
  const int nbb = nrows / 64;        // 160 (gemm2 grid)

  char* p = (char*)d_ws;
  unsigned short* XbP = (unsigned short*)p; p += (size_t)nrows * LAT * 2;
  unsigned short* Hb  = (unsigned short*)p; p += (size_t)nrows * HID * 2;
  unsigned short* Zb  = (unsigned short*)p; p += (size_t)nrows * HID * 2;
  unsigned short* W1P = (unsigned short*)p; p += (size_t)LAT * HID * 2;
  unsigned short* W2T = (unsigned short*)p; p += (size_t)HID * HID * 2;
  float* pS = (float*)p;  p += (size_t)nst * HID * 4;
  float* pQ = (float*)p;  p += (size_t)nst * HID * 4;
  float* nrmAll = (float*)p; p += (size_t)nrows * 4;
  float* n1v = nrmAll;
  float* n2v = nrmAll + nx;
  unsigned short* Z1b = Zb;
  unsigned short* Z2b = Zb + (size_t)nx * HID;

  const int xblocks = (nrows * LAT) / 2048;  // 2560
  k_prep<<<20 + xblocks, 256, 0, stream>>>(w1, w2, variations, exemplar, nx,
                                           W1P, W2T, XbP);
  k_gemm1<<<nst, 256, 0, stream>>>(XbP, W1P, Hb, pS, pQ);
  k_gemm2<<<nbb, 256, 0, stream>>>(Hb, W2T, pS, pQ, gamma, beta, Zb, nrmAll,
                                   pb1, nst, (float)nx, (float)ny, nx);
  const int ntx = ny / 128;          // 16
  const int nwg = (nx / 128) * ntx;  // 1024
  k_dist<<<nwg, 256, 0, stream>>>(Z1b, Z2b, n1v, n2v, D, ny, ntx);
}

// Round 16
// 57.263 us; speedup vs baseline: 1.1974x; 1.1974x over previous
//
#include <hip/hip_runtime.h>
#include <hip/hip_bf16.h>

// proto_net_loss, 4 dispatches (r13 structure). All MFMA operands fragment-packed.
//  prep:   W1P, W2T, XbP (fragment-packed bf16)
//  gemm1:  160 blocks x 4 waves (wave = 16 rows x 128 cols, K=512);
//          depth-4 register-pipelined operand loads + launch_bounds(256,1)
//  gemm2:  [BN finalize in head] Z(packed) = relu(H*sc+sh)@W2 + f32 row norms
//  dist:   D = n1[i]+n2[j]-2*Z1@Z2^T; packed Z loads, float4 stores, XCD swizzle

#define LAT 512
#define HID 128
#define EPSV 1e-5f

typedef __attribute__((ext_vector_type(8))) short bf16x8;
typedef __attribute__((ext_vector_type(4))) float f32x4;

__device__ __forceinline__ unsigned short f2bf(float x) {  // RTNE
  unsigned int u = __builtin_bit_cast(unsigned int, x);
  return (unsigned short)((u + 0x7fffu + ((u >> 16) & 1u)) >> 16);
}
__device__ __forceinline__ float bf2f(unsigned short h) {
  unsigned int u = ((unsigned int)h) << 16;
  return __builtin_bit_cast(float, u);
}
// packed store offset for acc[f][0..3] by lane (l15,lq) into [rows][128] tensor
__device__ __forceinline__ size_t pack4_off(int strip, int f, int l15, int lq) {
  return (size_t)strip * 2048 + (size_t)(f >> 1) * 512 + (size_t)l15 * 32 +
         (size_t)(((f & 1) * 2 + (lq >> 1)) * 8 + (lq & 1) * 4);
}

// ---------------- prep: W1P packed, W2T transposed, XbP packed ----------------
__global__ __launch_bounds__(256) void k_prep(const float* __restrict__ W1,
                                              const float* __restrict__ W2,
                                              const float* __restrict__ X1,
                                              const float* __restrict__ X2, int nx,
                                              unsigned short* __restrict__ W1P,
                                              unsigned short* __restrict__ W2T,
                                              unsigned short* __restrict__ XbP) {
  __shared__ float T[64][65];
  const int t = threadIdx.x;
  int bi = blockIdx.x;
  if (bi >= 20) {
    const size_t base = (size_t)(bi - 20) * 2048 + (size_t)t * 8;
    const size_t nxe = (size_t)nx * LAT;
    const float* src = (base < nxe) ? (X1 + base) : (X2 + (base - nxe));
    const float4 a = *(const float4*)src;
    const float4 b = *(const float4*)(src + 4);
    const int row = (int)(base >> 9);
    const int k = (int)(base & 511);
    const int st = row >> 4, l15 = row & 15;
    const int tf = k >> 5, lq = (k >> 3) & 3;
    const size_t off = ((((size_t)st * 16 + tf) * 16 + l15) * 4 + lq) * 8;
    const ushort4 o0 = {f2bf(a.x), f2bf(a.y), f2bf(a.z), f2bf(a.w)};
    const ushort4 o1 = {f2bf(b.x), f2bf(b.y), f2bf(b.z), f2bf(b.w)};
    *(ushort4*)(XbP + off) = o0;
    *(ushort4*)(XbP + off + 4) = o1;
    return;
  }
  if (bi < 16) {  // W1 -> W1P
    const int tk = bi >> 1, tn = bi & 1;
    const int k0 = tk * 64, n0 = tn * 64;
    {
      const int rr = t >> 4, cc = (t & 15) * 4;
#pragma unroll
      for (int i = 0; i < 4; ++i) {
        const int r = rr + i * 16;
        const float4 v = *(const float4*)(W1 + (size_t)(k0 + r) * HID + n0 + cc);
        T[cc + 0][r] = v.x; T[cc + 1][r] = v.y; T[cc + 2][r] = v.z; T[cc + 3][r] = v.w;
      }
    }
    __syncthreads();
    {
      const int nn = t >> 2, q = (t & 3) * 16;
      const int n = n0 + nn;
      const int f = n >> 4, l15 = n & 15;
#pragma unroll
      for (int e8 = 0; e8 < 2; ++e8) {
        const int kq = q + e8 * 8;
        const int kk = k0 + kq;
        const int tf = kk >> 5, lq = (kk >> 3) & 3;
        const size_t off = ((((size_t)f * 16 + tf) * 16 + l15) * 4 + lq) * 8;
        const ushort4 lo = {f2bf(T[nn][kq + 0]), f2bf(T[nn][kq + 1]),
                            f2bf(T[nn][kq + 2]), f2bf(T[nn][kq + 3])};
        const ushort4 hi = {f2bf(T[nn][kq + 4]), f2bf(T[nn][kq + 5]),
                            f2bf(T[nn][kq + 6]), f2bf(T[nn][kq + 7])};
        *(ushort4*)(W1P + off) = lo;
        *(ushort4*)(W1P + off + 4) = hi;
      }
    }
  } else {  // W2 -> W2T
    bi -= 16;
    const int tk = bi >> 1, tn = bi & 1;
    const int k0 = tk * 64, n0 = tn * 64;
    {
      const int rr = t >> 4, cc = (t & 15) * 4;
#pragma unroll
      for (int i = 0; i < 4; ++i) {
        const int r = rr + i * 16;
        const float4 v = *(const float4*)(W2 + (size_t)(k0 + r) * HID + n0 + cc);
        T[cc + 0][r] = v.x; T[cc + 1][r] = v.y; T[cc + 2][r] = v.z; T[cc + 3][r] = v.w;
      }
    }
    __syncthreads();
    {
      const int nn = t >> 2, q = (t & 3) * 16;
      unsigned short* dp = W2T + (size_t)(n0 + nn) * HID + k0 + q;
#pragma unroll
      for (int j = 0; j < 4; ++j) {
        ushort4 o = {f2bf(T[nn][q + j * 4 + 0]), f2bf(T[nn][q + j * 4 + 1]),
                     f2bf(T[nn][q + j * 4 + 2]), f2bf(T[nn][q + j * 4 + 3])};
        *(ushort4*)(dp + j * 4) = o;
      }
    }
  }
}

// ---------------- gemm1: depth-4 register-pipelined, 160 blocks x 4 waves ----------
__global__ __launch_bounds__(256, 1) void k_gemm1(
    const unsigned short* __restrict__ XbP,
    const unsigned short* __restrict__ W1P, unsigned short* __restrict__ H,
    float* __restrict__ pS, float* __restrict__ pQ) {
  __shared__ float sS[16][HID], sQ[16][HID];
  const int tid = threadIdx.x, wid = tid >> 6, lane = tid & 63;
  const int l15 = lane & 15, lq = lane >> 4;
  const int row0 = (int)blockIdx.x * 64 + wid * 16;
  const int strip = row0 >> 4;
  const unsigned short* xp = XbP + (size_t)strip * 8192 + (size_t)l15 * 32 + lq * 8;
  const unsigned short* wp = W1P + (size_t)l15 * 32 + lq * 8;
  f32x4 acc[8];
#pragma unroll
  for (int f = 0; f < 8; ++f) acc[f] = (f32x4){0.f, 0.f, 0.f, 0.f};

  // depth-4 software pipeline (fully unrolled -> static indexing)
  bf16x8 xb[4];
  bf16x8 ab[4][8];
#pragma unroll
  for (int p = 0; p < 4; ++p) {
    xb[p] = *(const bf16x8*)(xp + (size_t)p * 512);
#pragma unroll
    for (int f = 0; f < 8; ++f)
      ab[p][f] = *(const bf16x8*)(wp + (size_t)(f * 16 + p) * 512);
  }
#pragma unroll
  for (int t = 0; t < 16; ++t) {
    const int s = t & 3;
#pragma unroll
    for (int f = 0; f < 8; ++f) {
      acc[f] = __builtin_amdgcn_mfma_f32_16x16x32_bf16(ab[s][f], xb[s], acc[f], 0, 0, 0);
      if (t + 4 < 16)
        ab[s][f] = *(const bf16x8*)(wp + (size_t)(f * 16 + t + 4) * 512);
    }
    if (t + 4 < 16) xb[s] = *(const bf16x8*)(xp + (size_t)(t + 4) * 512);
  }
  // store H fragment-packed
#pragma unroll
  for (int f = 0; f < 8; ++f) {
    ushort4 hz = {f2bf(acc[f][0]), f2bf(acc[f][1]), f2bf(acc[f][2]), f2bf(acc[f][3])};
    *(ushort4*)(H + pack4_off(strip, f, l15, lq)) = hz;
  }
  // partial stats
#pragma unroll
  for (int f = 0; f < 8; ++f) {
    f32x4 s = acc[f];
    f32x4 q = acc[f] * acc[f];
#pragma unroll
    for (int r = 0; r < 4; ++r) {
      s[r] += __shfl_xor(s[r], 1, 64);
      q[r] += __shfl_xor(q[r], 1, 64);
      s[r] += __shfl_xor(s[r], 2, 64);
      q[r] += __shfl_xor(q[r], 2, 64);
    }
    if ((l15 & 3) == 0) {
      *(f32x4*)&sS[wid * 4 + (l15 >> 2)][f * 16 + lq * 4] = s;
      *(f32x4*)&sQ[wid * 4 + (l15 >> 2)][f * 16 + lq * 4] = q;
    }
  }
  __syncthreads();
  if (tid < HID) {
    float s = 0.f, q = 0.f;
#pragma unroll
    for (int r = 0; r < 16; ++r) { s += sS[r][tid]; q += sQ[r][tid]; }
    pS[(size_t)blockIdx.x * HID + tid] = s;
    pQ[(size_t)blockIdx.x * HID + tid] = q;
  }
}

// ---------------- gemm2: finalize-in-head + Z(packed) = relu(H*sc+sh)@W2 + norms ----
__global__ __launch_bounds__(256) void k_gemm2(
    const unsigned short* __restrict__ H,
    const unsigned short* __restrict__ W2T,
    const float* __restrict__ pS, const float* __restrict__ pQ,
    const float* __restrict__ gamma, const float* __restrict__ beta,
    unsigned short* __restrict__ Z, float* __restrict__ nrm,
    int nb1, int nblk, float n1c, float n2c) {
  __shared__ float s_sc[HID], s_sh[HID];
  __shared__ float t0[2][HID], t1[2][HID];
  const int tid = threadIdx.x, wid = tid >> 6, lane = tid & 63;
  const int l15 = lane & 15, lq = lane >> 4, lk8 = lq * 8;
  const bool set1 = (int)blockIdx.x < nb1;
  {
    const int col = tid & 127, half = tid >> 7;
    const int b0 = set1 ? 0 : nb1;
    const int nb = set1 ? nb1 : (nblk - nb1);
    float s = 0.f, q = 0.f;
#pragma unroll 4
    for (int b = half; b < nb; b += 2) {
      s += pS[(size_t)(b0 + b) * HID + col];
      q += pQ[(size_t)(b0 + b) * HID + col];
    }
    t0[half][col] = s;
    t1[half][col] = q;
  }
  __syncthreads();
  if (tid < HID) {
    const float s = t0[0][tid] + t0[1][tid];
    const float q = t1[0][tid] + t1[1][tid];
    const float n = set1 ? n1c : n2c;
    const float mean = s / n;
    const float var = q / n - mean * mean;
    const float rstd = rsqrtf(var + EPSV);
    const float scale = gamma[tid] * rstd;
    s_sc[tid] = scale;
    s_sh[tid] = beta[tid] - mean * scale;
  }
  __syncthreads();
  const int row0 = (int)blockIdx.x * 64 + wid * 16;
  const int strip = row0 >> 4;
  const unsigned short* hptr = H + (size_t)strip * 2048 + (size_t)l15 * 32 + lk8;
  f32x4 acc[8];
#pragma unroll
  for (int f = 0; f < 8; ++f) acc[f] = (f32x4){0.f, 0.f, 0.f, 0.f};
#pragma unroll
  for (int s = 0; s < 4; ++s) {
    const int k = s * 32 + lk8;
    const bf16x8 hv = *(const bf16x8*)(hptr + (size_t)s * 512);
    const float4 c0 = *(const float4*)&s_sc[k];
    const float4 c1 = *(const float4*)&s_sc[k + 4];
    const float4 d0 = *(const float4*)&s_sh[k];
    const float4 d1 = *(const float4*)&s_sh[k + 4];
    const float cc[8] = {c0.x, c0.y, c0.z, c0.w, c1.x, c1.y, c1.z, c1.w};
    const float dd[8] = {d0.x, d0.y, d0.z, d0.w, d1.x, d1.y, d1.z, d1.w};
    bf16x8 bfr;
#pragma unroll
    for (int i = 0; i < 8; ++i) {
      const float a = fmaxf(fmaf(bf2f((unsigned short)hv[i]), cc[i], dd[i]), 0.f);
      bfr[i] = (short)f2bf(a);
    }
#pragma unroll
    for (int f = 0; f < 8; ++f) {
      const bf16x8 afr = *(const bf16x8*)(W2T + (size_t)(f * 16 + l15) * HID + k);
      acc[f] = __builtin_amdgcn_mfma_f32_16x16x32_bf16(afr, bfr, acc[f], 0, 0, 0);
    }
  }
  float rn = 0.f;
#pragma unroll
  for (int f = 0; f < 8; ++f) {
    rn += acc[f][0] * acc[f][0] + acc[f][1] * acc[f][1] +
          acc[f][2] * acc[f][2] + acc[f][3] * acc[f][3];
    ushort4 z4 = {f2bf(acc[f][0]), f2bf(acc[f][1]), f2bf(acc[f][2]), f2bf(acc[f][3])};
    *(ushort4*)(Z + pack4_off(strip, f, l15, lq)) = z4;
  }
  rn += __shfl_xor(rn, 16, 64);
  rn += __shfl_xor(rn, 32, 64);
  if (lane < 16) nrm[row0 + l15] = rn;
}

// ---------------- dist: packed Z loads, float4 stores, XCD swizzle ----------------
__global__ __launch_bounds__(256) void k_dist(const unsigned short* __restrict__ Z1b,
                                              const unsigned short* __restrict__ Z2b,
                                              const float* __restrict__ n1,
                                              const float* __restrict__ n2,
                                              float* __restrict__ D, int NY, int ntx) {
  const int nwg = (int)gridDim.x;
  const int cpx = nwg >> 3;
  const int bid = (int)blockIdx.x;
  const int wgid = (bid & 7) * cpx + (bid >> 3);
  const int tby = wgid / ntx, tbx = wgid - tby * ntx;

  const int tid = threadIdx.x;
  const int wid = tid >> 6, lane = tid & 63;
  const int wr = wid >> 1, wc = wid & 1;
  const int rowB = tby * 128 + wr * 64;
  const int colB = tbx * 128 + wc * 64;
  const int l15 = lane & 15, lq = lane >> 4;
  const unsigned short* Ap = Z1b + (size_t)(rowB >> 4) * 2048 + (size_t)l15 * 32 + lq * 8;
  const unsigned short* Bp = Z2b + (size_t)(colB >> 4) * 2048 + (size_t)l15 * 32 + lq * 8;
  f32x4 acc[4][4];
#pragma unroll
  for (int i = 0; i < 4; ++i)
#pragma unroll
    for (int j = 0; j < 4; ++j) acc[i][j] = (f32x4){0.f, 0.f, 0.f, 0.f};
#pragma unroll
  for (int s = 0; s < 4; ++s) {
    bf16x8 a[4], b[4];
#pragma unroll
    for (int i = 0; i < 4; ++i) a[i] = *(const bf16x8*)(Ap + (size_t)i * 2048 + (size_t)s * 512);
#pragma unroll
    for (int j = 0; j < 4; ++j) b[j] = *(const bf16x8*)(Bp + (size_t)j * 2048 + (size_t)s * 512);
#pragma unroll
    for (int i = 0; i < 4; ++i)
#pragma unroll
      for (int j = 0; j < 4; ++j)
        acc[i][j] = __builtin_amdgcn_mfma_f32_16x16x32_bf16(b[j], a[i], acc[i][j], 0, 0, 0);
  }
  const int cq = lq * 4;
  float na[4];
#pragma unroll
  for (int i = 0; i < 4; ++i) na[i] = n1[rowB + i * 16 + l15];
#pragma unroll
  for (int j = 0; j < 4; ++j) {
    const float4 nbv = *(const float4*)(n2 + colB + j * 16 + cq);
#pragma unroll
    for (int i = 0; i < 4; ++i) {
      float4 o;
      o.x = na[i] + nbv.x - 2.f * acc[i][j][0];
      o.y = na[i] + nbv.y - 2.f * acc[i][j][1];
      o.z = na[i] + nbv.z - 2.f * acc[i][j][2];
      o.w = na[i] + nbv.w - 2.f * acc[i][j][3];
      *(float4*)(D + (size_t)(rowB + i * 16 + l15) * NY + colB + j * 16 + cq) = o;
    }
  }
}

extern "C" void kernel_launch(void* const* d_in, const int* in_sizes, int n_in,
                              void* d_out, int out_size, void* d_ws, size_t ws_size,
                              hipStream_t stream) {
  const float* variations = (const float*)d_in[0];
  const float* exemplar   = (const float*)d_in[1];
  const float* w1         = (const float*)d_in[2];
  const float* gamma      = (const float*)d_in[3];
  const float* beta       = (const float*)d_in[4];
  const float* w2         = (const float*)d_in[5];
  float* D = (float*)d_out;

  const int nx = in_sizes[0] / LAT;  // 8192
  const int ny = in_sizes[1] / LAT;  // 2048
  const int nrows = nx + ny;         // 10240
  const int nbb = nrows / 64;        // 160
  const int nb1 = nx / 64;           // 128

  char* p = (char*)d_ws;
  unsigned short* XbP = (unsigned short*)p; p += (size_t)nrows * LAT * 2;
  unsigned short* Hb  = (unsigned short*)p; p += (size_t)nrows * HID * 2;
  unsigned short* Zb  = (unsigned short*)p; p += (size_t)nrows * HID * 2;
  unsigned short* W1P = (unsigned short*)p; p += (size_t)LAT * HID * 2;
  unsigned short* W2T = (unsigned short*)p; p += (size_t)HID * HID * 2;
  float* pS = (float*)p;  p += (size_t)nbb * HID * 4;
  float* pQ = (float*)p;  p += (size_t)nbb * HID * 4;
  float* nrmAll = (float*)p; p += (size_t)nrows * 4;
  float* n1v = nrmAll;
  float* n2v = nrmAll + nx;
  unsigned short* Z1b = Zb;
  unsigned short* Z2b = Zb + (size_t)nx * HID;

  const int xblocks = (nrows * LAT) / 2048;  // 2560
  k_prep<<<20 + xblocks, 256, 0, stream>>>(w1, w2, variations, exemplar, nx,
                                           W1P, W2T, XbP);
  k_gemm1<<<nbb, 256, 0, stream>>>(XbP, W1P, Hb, pS, pQ);
  k_gemm2<<<nbb, 256, 0, stream>>>(Hb, W2T, pS, pQ, gamma, beta, Zb, nrmAll,
                                   nb1, nbb, (float)nx, (float)ny);
  const int ntx = ny / 128;          // 16
  const int nwg = (nx / 128) * ntx;  // 1024
  k_dist<<<nwg, 256, 0, stream>>>(Z1b, Z2b, n1v, n2v, D, ny, ntx);
}

// Round 17
// 57.076 us; speedup vs baseline: 1.2013x; 1.0033x over previous
//
#include <hip/hip_runtime.h>
#include <hip/hip_bf16.h>

// proto_net_loss, 4 dispatches:
//  prep:   weights only (20 blocks): W1P fragment-packed bf16, W2T transposed bf16
//  gemm1:  160 blocks x 4 waves (wave = 16 rows x 128 cols, K=512);
//          X read directly as f32 (fragment-row order) + in-register bf16 convert;
//          depth-4 register pipeline on W1P + X; fused BN partial stats
//  gemm2:  [BN finalize in head] Z(packed) = relu(H*sc+sh)@W2 + f32 row norms
//  dist:   D = n1[i]+n2[j]-2*Z1@Z2^T; packed Z loads, float4 stores, XCD swizzle

#define LAT 512
#define HID 128
#define EPSV 1e-5f

typedef __attribute__((ext_vector_type(8))) short bf16x8;
typedef __attribute__((ext_vector_type(4))) float f32x4;

__device__ __forceinline__ unsigned short f2bf(float x) {  // RTNE
  unsigned int u = __builtin_bit_cast(unsigned int, x);
  return (unsigned short)((u + 0x7fffu + ((u >> 16) & 1u)) >> 16);
}
__device__ __forceinline__ float bf2f(unsigned short h) {
  unsigned int u = ((unsigned int)h) << 16;
  return __builtin_bit_cast(float, u);
}
// packed store offset for acc[f][0..3] by lane (l15,lq) into [rows][128] tensor
__device__ __forceinline__ size_t pack4_off(int strip, int f, int l15, int lq) {
  return (size_t)strip * 2048 + (size_t)(f >> 1) * 512 + (size_t)l15 * 32 +
         (size_t)(((f & 1) * 2 + (lq >> 1)) * 8 + (lq & 1) * 4);
}

// ---------------- prep: weights only (blocks 0..15 W1 -> W1P, 16..19 W2 -> W2T) ----
__global__ __launch_bounds__(256) void k_prep(const float* __restrict__ W1,
                                              const float* __restrict__ W2,
                                              unsigned short* __restrict__ W1P,
                                              unsigned short* __restrict__ W2T) {
  __shared__ float T[64][65];
  const int t = threadIdx.x;
  int bi = blockIdx.x;
  if (bi < 16) {  // W1 -> W1P fragment-packed
    const int tk = bi >> 1, tn = bi & 1;
    const int k0 = tk * 64, n0 = tn * 64;
    {
      const int rr = t >> 4, cc = (t & 15) * 4;
#pragma unroll
      for (int i = 0; i < 4; ++i) {
        const int r = rr + i * 16;
        const float4 v = *(const float4*)(W1 + (size_t)(k0 + r) * HID + n0 + cc);
        T[cc + 0][r] = v.x; T[cc + 1][r] = v.y; T[cc + 2][r] = v.z; T[cc + 3][r] = v.w;
      }
    }
    __syncthreads();
    {
      const int nn = t >> 2, q = (t & 3) * 16;
      const int n = n0 + nn;
      const int f = n >> 4, l15 = n & 15;
#pragma unroll
      for (int e8 = 0; e8 < 2; ++e8) {
        const int kq = q + e8 * 8;
        const int kk = k0 + kq;
        const int tf = kk >> 5, lq = (kk >> 3) & 3;
        const size_t off = ((((size_t)f * 16 + tf) * 16 + l15) * 4 + lq) * 8;
        const ushort4 lo = {f2bf(T[nn][kq + 0]), f2bf(T[nn][kq + 1]),
                            f2bf(T[nn][kq + 2]), f2bf(T[nn][kq + 3])};
        const ushort4 hi = {f2bf(T[nn][kq + 4]), f2bf(T[nn][kq + 5]),
                            f2bf(T[nn][kq + 6]), f2bf(T[nn][kq + 7])};
        *(ushort4*)(W1P + off) = lo;
        *(ushort4*)(W1P + off + 4) = hi;
      }
    }
  } else {  // W2 -> W2T row-major transposed
    bi -= 16;
    const int tk = bi >> 1, tn = bi & 1;
    const int k0 = tk * 64, n0 = tn * 64;
    {
      const int rr = t >> 4, cc = (t & 15) * 4;
#pragma unroll
      for (int i = 0; i < 4; ++i) {
        const int r = rr + i * 16;
        const float4 v = *(const float4*)(W2 + (size_t)(k0 + r) * HID + n0 + cc);
        T[cc + 0][r] = v.x; T[cc + 1][r] = v.y; T[cc + 2][r] = v.z; T[cc + 3][r] = v.w;
      }
    }
    __syncthreads();
    {
      const int nn = t >> 2, q = (t & 3) * 16;
      unsigned short* dp = W2T + (size_t)(n0 + nn) * HID + k0 + q;
#pragma unroll
      for (int j = 0; j < 4; ++j) {
        ushort4 o = {f2bf(T[nn][q + j * 4 + 0]), f2bf(T[nn][q + j * 4 + 1]),
                     f2bf(T[nn][q + j * 4 + 2]), f2bf(T[nn][q + j * 4 + 3])};
        *(ushort4*)(dp + j * 4) = o;
      }
    }
  }
}

// ---------------- gemm1: X f32 direct + depth-4 pipeline, 160 blocks x 4 waves ------
__global__ __launch_bounds__(256, 1) void k_gemm1(
    const float* __restrict__ X1, const float* __restrict__ X2, int nx,
    const unsigned short* __restrict__ W1P, unsigned short* __restrict__ H,
    float* __restrict__ pS, float* __restrict__ pQ) {
  __shared__ float sS[16][HID], sQ[16][HID];
  const int tid = threadIdx.x, wid = tid >> 6, lane = tid & 63;
  const int l15 = lane & 15, lq = lane >> 4;
  const int browBase = (int)blockIdx.x * 64;
  const int row0 = browBase + wid * 16;
  const int strip = row0 >> 4;
  const float* X = (browBase < nx) ? X1 : X2;
  const int xrow = (browBase < nx) ? row0 : row0 - nx;
  const float* xptr = X + (size_t)(xrow + l15) * LAT + lq * 8;
  const unsigned short* wp = W1P + (size_t)l15 * 32 + lq * 8;
  f32x4 acc[8];
#pragma unroll
  for (int f = 0; f < 8; ++f) acc[f] = (f32x4){0.f, 0.f, 0.f, 0.f};

  // depth-4 software pipeline: W fragments in bf16, X in raw f32 (convert at use)
  float4 xa[4], xb4[4];
  bf16x8 ab[4][8];
#pragma unroll
  for (int p = 0; p < 4; ++p) {
    xa[p] = *(const float4*)(xptr + p * 32);
    xb4[p] = *(const float4*)(xptr + p * 32 + 4);
#pragma unroll
    for (int f = 0; f < 8; ++f)
      ab[p][f] = *(const bf16x8*)(wp + (size_t)(f * 16 + p) * 512);
  }
#pragma unroll
  for (int t = 0; t < 16; ++t) {
    const int s = t & 3;
    const float vv[8] = {xa[s].x, xa[s].y, xa[s].z, xa[s].w,
                         xb4[s].x, xb4[s].y, xb4[s].z, xb4[s].w};
    bf16x8 xv;
#pragma unroll
    for (int i = 0; i < 8; ++i) xv[i] = (short)f2bf(vv[i]);
    if (t + 4 < 16) {
      xa[s] = *(const float4*)(xptr + (t + 4) * 32);
      xb4[s] = *(const float4*)(xptr + (t + 4) * 32 + 4);
    }
#pragma unroll
    for (int f = 0; f < 8; ++f) {
      acc[f] = __builtin_amdgcn_mfma_f32_16x16x32_bf16(ab[s][f], xv, acc[f], 0, 0, 0);
      if (t + 4 < 16)
        ab[s][f] = *(const bf16x8*)(wp + (size_t)(f * 16 + t + 4) * 512);
    }
  }
  // store H fragment-packed
#pragma unroll
  for (int f = 0; f < 8; ++f) {
    ushort4 hz = {f2bf(acc[f][0]), f2bf(acc[f][1]), f2bf(acc[f][2]), f2bf(acc[f][3])};
    *(ushort4*)(H + pack4_off(strip, f, l15, lq)) = hz;
  }
  // partial stats
#pragma unroll
  for (int f = 0; f < 8; ++f) {
    f32x4 s = acc[f];
    f32x4 q = acc[f] * acc[f];
#pragma unroll
    for (int r = 0; r < 4; ++r) {
      s[r] += __shfl_xor(s[r], 1, 64);
      q[r] += __shfl_xor(q[r], 1, 64);
      s[r] += __shfl_xor(s[r], 2, 64);
      q[r] += __shfl_xor(q[r], 2, 64);
    }
    if ((l15 & 3) == 0) {
      *(f32x4*)&sS[wid * 4 + (l15 >> 2)][f * 16 + lq * 4] = s;
      *(f32x4*)&sQ[wid * 4 + (l15 >> 2)][f * 16 + lq * 4] = q;
    }
  }
  __syncthreads();
  if (tid < HID) {
    float s = 0.f, q = 0.f;
#pragma unroll
    for (int r = 0; r < 16; ++r) { s += sS[r][tid]; q += sQ[r][tid]; }
    pS[(size_t)blockIdx.x * HID + tid] = s;
    pQ[(size_t)blockIdx.x * HID + tid] = q;
  }
}

// ---------------- gemm2: finalize-in-head + Z(packed) = relu(H*sc+sh)@W2 + norms ----
__global__ __launch_bounds__(256) void k_gemm2(
    const unsigned short* __restrict__ H,
    const unsigned short* __restrict__ W2T,
    const float* __restrict__ pS, const float* __restrict__ pQ,
    const float* __restrict__ gamma, const float* __restrict__ beta,
    unsigned short* __restrict__ Z, float* __restrict__ nrm,
    int nb1, int nblk, float n1c, float n2c) {
  __shared__ float s_sc[HID], s_sh[HID];
  __shared__ float t0[2][HID], t1[2][HID];
  const int tid = threadIdx.x, wid = tid >> 6, lane = tid & 63;
  const int l15 = lane & 15, lq = lane >> 4, lk8 = lq * 8;
  const bool set1 = (int)blockIdx.x < nb1;
  {
    const int col = tid & 127, half = tid >> 7;
    const int b0 = set1 ? 0 : nb1;
    const int nb = set1 ? nb1 : (nblk - nb1);
    float s = 0.f, q = 0.f;
#pragma unroll 4
    for (int b = half; b < nb; b += 2) {
      s += pS[(size_t)(b0 + b) * HID + col];
      q += pQ[(size_t)(b0 + b) * HID + col];
    }
    t0[half][col] = s;
    t1[half][col] = q;
  }
  __syncthreads();
  if (tid < HID) {
    const float s = t0[0][tid] + t0[1][tid];
    const float q = t1[0][tid] + t1[1][tid];
    const float n = set1 ? n1c : n2c;
    const float mean = s / n;
    const float var = q / n - mean * mean;
    const float rstd = rsqrtf(var + EPSV);
    const float scale = gamma[tid] * rstd;
    s_sc[tid] = scale;
    s_sh[tid] = beta[tid] - mean * scale;
  }
  __syncthreads();
  const int row0 = (int)blockIdx.x * 64 + wid * 16;
  const int strip = row0 >> 4;
  const unsigned short* hptr = H + (size_t)strip * 2048 + (size_t)l15 * 32 + lk8;
  f32x4 acc[8];
#pragma unroll
  for (int f = 0; f < 8; ++f) acc[f] = (f32x4){0.f, 0.f, 0.f, 0.f};
#pragma unroll
  for (int s = 0; s < 4; ++s) {
    const int k = s * 32 + lk8;
    const bf16x8 hv = *(const bf16x8*)(hptr + (size_t)s * 512);
    const float4 c0 = *(const float4*)&s_sc[k];
    const float4 c1 = *(const float4*)&s_sc[k + 4];
    const float4 d0 = *(const float4*)&s_sh[k];
    const float4 d1 = *(const float4*)&s_sh[k + 4];
    const float cc[8] = {c0.x, c0.y, c0.z, c0.w, c1.x, c1.y, c1.z, c1.w};
    const float dd[8] = {d0.x, d0.y, d0.z, d0.w, d1.x, d1.y, d1.z, d1.w};
    bf16x8 bfr;
#pragma unroll
    for (int i = 0; i < 8; ++i) {
      const float a = fmaxf(fmaf(bf2f((unsigned short)hv[i]), cc[i], dd[i]), 0.f);
      bfr[i] = (short)f2bf(a);
    }
#pragma unroll
    for (int f = 0; f < 8; ++f) {
      const bf16x8 afr = *(const bf16x8*)(W2T + (size_t)(f * 16 + l15) * HID + k);
      acc[f] = __builtin_amdgcn_mfma_f32_16x16x32_bf16(afr, bfr, acc[f], 0, 0, 0);
    }
  }
  float rn = 0.f;
#pragma unroll
  for (int f = 0; f < 8; ++f) {
    rn += acc[f][0] * acc[f][0] + acc[f][1] * acc[f][1] +
          acc[f][2] * acc[f][2] + acc[f][3] * acc[f][3];
    ushort4 z4 = {f2bf(acc[f][0]), f2bf(acc[f][1]), f2bf(acc[f][2]), f2bf(acc[f][3])};
    *(ushort4*)(Z + pack4_off(strip, f, l15, lq)) = z4;
  }
  rn += __shfl_xor(rn, 16, 64);
  rn += __shfl_xor(rn, 32, 64);
  if (lane < 16) nrm[row0 + l15] = rn;
}

// ---------------- dist: packed Z loads, float4 stores, XCD swizzle ----------------
__global__ __launch_bounds__(256) void k_dist(const unsigned short* __restrict__ Z1b,
                                              const unsigned short* __restrict__ Z2b,
                                              const float* __restrict__ n1,
                                              const float* __restrict__ n2,
                                              float* __restrict__ D, int NY, int ntx) {
  const int nwg = (int)gridDim.x;
  const int cpx = nwg >> 3;
  const int bid = (int)blockIdx.x;
  const int wgid = (bid & 7) * cpx + (bid >> 3);
  const int tby = wgid / ntx, tbx = wgid - tby * ntx;

  const int tid = threadIdx.x;
  const int wid = tid >> 6, lane = tid & 63;
  const int wr = wid >> 1, wc = wid & 1;
  const int rowB = tby * 128 + wr * 64;
  const int colB = tbx * 128 + wc * 64;
  const int l15 = lane & 15, lq = lane >> 4;
  const unsigned short* Ap = Z1b + (size_t)(rowB >> 4) * 2048 + (size_t)l15 * 32 + lq * 8;
  const unsigned short* Bp = Z2b + (size_t)(colB >> 4) * 2048 + (size_t)l15 * 32 + lq * 8;
  f32x4 acc[4][4];
#pragma unroll
  for (int i = 0; i < 4; ++i)
#pragma unroll
    for (int j = 0; j < 4; ++j) acc[i][j] = (f32x4){0.f, 0.f, 0.f, 0.f};
#pragma unroll
  for (int s = 0; s < 4; ++s) {
    bf16x8 a[4], b[4];
#pragma unroll
    for (int i = 0; i < 4; ++i) a[i] = *(const bf16x8*)(Ap + (size_t)i * 2048 + (size_t)s * 512);
#pragma unroll
    for (int j = 0; j < 4; ++j) b[j] = *(const bf16x8*)(Bp + (size_t)j * 2048 + (size_t)s * 512);
#pragma unroll
    for (int i = 0; i < 4; ++i)
#pragma unroll
      for (int j = 0; j < 4; ++j)
        acc[i][j] = __builtin_amdgcn_mfma_f32_16x16x32_bf16(b[j], a[i], acc[i][j], 0, 0, 0);
  }
  const int cq = lq * 4;
  float na[4];
#pragma unroll
  for (int i = 0; i < 4; ++i) na[i] = n1[rowB + i * 16 + l15];
#pragma unroll
  for (int j = 0; j < 4; ++j) {
    const float4 nbv = *(const float4*)(n2 + colB + j * 16 + cq);
#pragma unroll
    for (int i = 0; i < 4; ++i) {
      float4 o;
      o.x = na[i] + nbv.x - 2.f * acc[i][j][0];
      o.y = na[i] + nbv.y - 2.f * acc[i][j][1];
      o.z = na[i] + nbv.z - 2.f * acc[i][j][2];
      o.w = na[i] + nbv.w - 2.f * acc[i][j][3];
      *(float4*)(D + (size_t)(rowB + i * 16 + l15) * NY + colB + j * 16 + cq) = o;
    }
  }
}

extern "C" void kernel_launch(void* const* d_in, const int* in_sizes, int n_in,
                              void* d_out, int out_size, void* d_ws, size_t ws_size,
                              hipStream_t stream) {
  const float* variations = (const float*)d_in[0];
  const float* exemplar   = (const float*)d_in[1];
  const float* w1         = (const float*)d_in[2];
  const float* gamma      = (const float*)d_in[3];
  const float* beta       = (const float*)d_in[4];
  const float* w2         = (const float*)d_in[5];
  float* D = (float*)d_out;

  const int nx = in_sizes[0] / LAT;  // 8192
  const int ny = in_sizes[1] / LAT;  // 2048
  const int nrows = nx + ny;         // 10240
  const int nbb = nrows / 64;        // 160
  const int nb1 = nx / 64;           // 128

  char* p = (char*)d_ws;
  unsigned short* Hb  = (unsigned short*)p; p += (size_t)nrows * HID * 2;
  unsigned short* Zb  = (unsigned short*)p; p += (size_t)nrows * HID * 2;
  unsigned short* W1P = (unsigned short*)p; p += (size_t)LAT * HID * 2;
  unsigned short* W2T = (unsigned short*)p; p += (size_t)HID * HID * 2;
  float* pS = (float*)p;  p += (size_t)nbb * HID * 4;
  float* pQ = (float*)p;  p += (size_t)nbb * HID * 4;
  float* nrmAll = (float*)p; p += (size_t)nrows * 4;
  float* n1v = nrmAll;
  float* n2v = nrmAll + nx;
  unsigned short* Z1b = Zb;
  unsigned short* Z2b = Zb + (size_t)nx * HID;

  k_prep<<<20, 256, 0, stream>>>(w1, w2, W1P, W2T);
  k_gemm1<<<nbb, 256, 0, stream>>>(variations, exemplar, nx, W1P, Hb, pS, pQ);
  k_gemm2<<<nbb, 256, 0, stream>>>(Hb, W2T, pS, pQ, gamma, beta, Zb, nrmAll,
                                   nb1, nbb, (float)nx, (float)ny);
  const int ntx = ny / 128;          // 16
  const int nwg = (nx / 128) * ntx;  // 1024
  k_dist<<<nwg, 256, 0, stream>>>(Z1b, Z2b, n1v, n2v, D, ny, ntx);
}